// Round 6
// baseline (102.522 us; speedup 1.0000x reference)
//
#include <hip/hip_runtime.h>

#define BATCH 64
#define NN 256
// Scaled DP domain: V' = V * CSC, CSC = (1/gamma)*log2(e), gamma = 0.01.
#define CSC   144.26950408889634f
#define RCSC  0.0069314718055994531f   // 1/CSC = gamma*ln(2)
#define BIGS  1.4426950408889634e10f   // 1e8 * CSC (scaled boundary)
#define OROW  576                      // per-wave padded o row
#define NGRP  70                       // 70*8 = 560 iters + 2 peeled = 562

// 4 waves per batch, 1 DP row per lane: wave w, lane l owns row i = 64w+l+1.
// Skew 17: at iter n, wave w computes diag k = n+2-17w (col j = n+1-81w-l).
// Intra-wave handoff: DPP wave_shr1; lane 0 receives the cross-wave boundary
// value through the DPP `old` operand. Cross-wave: lane 63 publishes (V',Ut)
// to a 32-slot LDS ring (slot = iter mod 32); consumer uses the value written
// 18 iters earlier, prefetched 8..15 iters ahead as 4x ds_read_b128 at the top
// of each 8-iter group. Raw s_barrier (no lgkmcnt drain) every 8 iters bounds
// wave drift; every prefetched slot was written >=2 iters (~300 cy) before its
// producer reached the intervening barrier, and DS completes in-order, so no
// drain is needed. o operand: per-wave phase-aligned copy oW[w] (o at offset
// 81w, zeros elsewhere) -> 2 broadcast float4 reads per group, DPP-flowed
// down-lane. BIG self-propagation (round-4-validated) makes all skew
// startup/tail cells harmless; ring pre-init = (BIGS, 0).
// Temporal term = JVP tangent of V[N,N] with seed omega[i,j] = (i-j)^2.

__device__ __forceinline__ float shr1(float x, float old) {
    return __int_as_float(__builtin_amdgcn_update_dpp(
        __float_as_int(old), __float_as_int(x), 0x138, 0xF, 0xF, false));
}

#define ITER(AX, AY, OINJ) {                                         \
    float sA = shr1(A, (AX));                                        \
    float sU = shr1(U, (AY));                                        \
    oc = shr1(oc, (OINJ));                                           \
    float m  = fminf(fminf(A, psA), sA);                             \
    float el = __builtin_amdgcn_exp2f(m - A);                        \
    float ed = __builtin_amdgcn_exp2f(m - psA);                      \
    float eu = __builtin_amdgcn_exp2f(m - sA);                       \
    float s  = el + ed + eu;                                         \
    float x  = T - oc;                                               \
    float nv = fmaf(CSC * x, x, m - __builtin_amdgcn_logf(s));       \
    float num = fmaf(el, U, fmaf(ed, psU, eu * sU));                 \
    float nt  = fmaf(num, __builtin_amdgcn_rcpf(s), dr * dr);        \
    if (l63) ringw[ws & 31u] = make_float2(nv, nt);                  \
    ++ws;                                                            \
    psA = sA; psU = sU; A = nv; U = nt; dr -= 1.0f;                  \
}

__global__ __launch_bounds__(256) void dilate_fused(
    const float* __restrict__ y_pred,
    const float* __restrict__ y_true,
    float* __restrict__ out)
{
    const int b   = blockIdx.x;
    const int tid = threadIdx.x;
    const int w   = tid >> 6;
    const int l   = tid & 63;
    const bool l63 = (l == 63);

    __shared__ float  oW[4][OROW];   // row w: o at [81w, 81w+256), zeros elsewhere
    __shared__ float2 ring[5][32];   // rows 0..3 = producer waves; row 4 = const BIGS

    {   // zero-fill oW (576 float4) + ring init
        float4* p = (float4*)oW;
        const float4 z4 = make_float4(0.f, 0.f, 0.f, 0.f);
        p[tid] = z4; p[tid + 256] = z4;
        if (tid < 64)  p[tid + 512] = z4;
        if (tid < 160) ((float2*)ring)[tid] = make_float2(BIGS, 0.f);
    }
    __syncthreads();
    {   // copy o into this wave's phase-shifted row
        const float4 ov = ((const float4*)(y_pred + b * NN))[l];
        float* dst = &oW[w][81 * w + 4 * l];
        dst[0] = ov.x; dst[1] = ov.y; dst[2] = ov.z; dst[3] = ov.w;
    }
    const float T = y_true[b * NN + tid];     // row i = tid+1
    __syncthreads();

    float A = BIGS, U = 0.f;
    float psA = (tid == 0) ? 0.f : BIGS;      // V[0,0] corner seed
    float psU = 0.f;
    float oc = 0.f;
    float dr = (float)(145 * w + 2 * l);      // (i - j) at iter 0

    float2* ringw = ring[w];
    const float* ringr = (const float*)((w == 0) ? ring[4] : ring[w - 1]);
    const float* orow = oW[w];
    unsigned ws = 0;

    // u pipeline: uses for iters 0..7 <- slots (n-18)&31 = 14..21 (pre-init)
    float4 ua = *(const float4*)(ringr + 14 * 2);
    float4 ub = *(const float4*)(ringr + 16 * 2);
    float4 uc = *(const float4*)(ringr + 18 * 2);
    float4 ud = *(const float4*)(ringr + 20 * 2);
    float4 coA = *(const float4*)(orow + 0);  // o for iters 0..3
    float4 coB = *(const float4*)(orow + 4);  // o for iters 4..7

    #pragma unroll 1
    for (int g = 0; g < NGRP; ++g) {
        const int S = g << 3;
        const int base = (S + 22) & 31;       // (S-10) mod 32; even -> 16B aligned
        const float4 na = *(const float4*)(ringr + ((base    ) & 31) * 2);
        const float4 nb = *(const float4*)(ringr + ((base + 2) & 31) * 2);
        const float4 nc = *(const float4*)(ringr + ((base + 4) & 31) * 2);
        const float4 nd = *(const float4*)(ringr + ((base + 6) & 31) * 2);
        const float4 noA = *(const float4*)(orow + S + 8);
        const float4 noB = *(const float4*)(orow + S + 12);
        ITER(ua.x, ua.y, coA.x) ITER(ua.z, ua.w, coA.y)
        ITER(ub.x, ub.y, coA.z) ITER(ub.z, ub.w, coA.w)
        ITER(uc.x, uc.y, coB.x) ITER(uc.z, uc.w, coB.y)
        ITER(ud.x, ud.y, coB.z) ITER(ud.z, ud.w, coB.w)
        __asm__ volatile("s_barrier" ::: "memory");
        ua = na; ub = nb; uc = nc; ud = nd;
        coA = noA; coB = noB;
    }
    // peel iters 560, 561 (wave 3 computes diag 512 at iter 561); their ring
    // inputs were prefetched at g=69 and written before the last barrier.
    ITER(ua.x, ua.y, coA.x)
    ITER(ua.z, ua.w, coA.y)

    if (tid == 255) {                         // wave 3, lane 63: cell (256,256)
        float loss = 0.5f * (A * RCSC) * (1.0f / BATCH)
                   + 0.5f * U * (1.0f / ((float)BATCH * (float)(NN * NN)));
        atomicAdd(out, loss);
    }
}

extern "C" void kernel_launch(void* const* d_in, const int* in_sizes, int n_in,
                              void* d_out, int out_size, void* d_ws, size_t ws_size,
                              hipStream_t stream)
{
    const float* y_pred = (const float*)d_in[0];   // [64,256,1] -> o (columns)
    const float* y_true = (const float*)d_in[1];   // [64,256,1] -> t (rows)
    hipMemsetAsync(d_out, 0, sizeof(float), stream);
    dilate_fused<<<BATCH, 256, 0, stream>>>(y_pred, y_true, (float*)d_out);
}